// Round 1
// baseline (5350.739 us; speedup 1.0000x reference)
//
#include <hip/hip_runtime.h>
#include <float.h>

#define NB 64
#define HD 1024
#define H3 3072
#define NV 32000
#define TSTEPS 32

__device__ __forceinline__ float sigmoidf_(float x) {
    return 1.0f / (1.0f + expf(-x));
}

// ---------------- init: h0 = [zs|cs], x0 = emb[SOS=1] ----------------
__global__ __launch_bounds__(256) void init_kernel(
    const float* __restrict__ zs, const float* __restrict__ cs,
    const float* __restrict__ emb, float* __restrict__ h, float* __restrict__ x)
{
    int b = blockIdx.x;
    int j = threadIdx.x * 4;
    float4 v;
    if (j < 512) v = *(const float4*)&zs[b * 512 + j];
    else         v = *(const float4*)&cs[b * 512 + (j - 512)];
    *(float4*)&h[b * HD + j] = v;
    *(float4*)&x[b * HD + j] = *(const float4*)&emb[1 * HD + j];  // SOS = 1
}

// ---------------- gates GEMM: gi = X@Wih^T, gh = H@Whh^T ----------------
// grid 96: blocks 0..47 -> gi cols, 48..95 -> gh cols. 64x64 tile, Kblk=32.
__global__ __launch_bounds__(256) void gates_gemm(
    const float* __restrict__ X, const float* __restrict__ Hc,
    const float* __restrict__ Wih, const float* __restrict__ Whh,
    float* __restrict__ gi, float* __restrict__ gh)
{
    int blk = blockIdx.x;
    bool isH = blk >= 48;
    const float* __restrict__ src = isH ? Hc : X;
    const float* __restrict__ W   = isH ? Whh : Wih;
    float* __restrict__ outp      = isH ? gh : gi;
    int col0 = (isH ? blk - 48 : blk) * 64;

    __shared__ float Xs[64][33];
    __shared__ float Ws[64][33];

    int tid  = threadIdx.x;
    int ty   = tid >> 4, tx = tid & 15;   // 16x16 threads, each 4x4 outputs
    int lrow = tid >> 3;                  // 0..31
    int lk4  = (tid & 7) << 2;            // 0..28 step 4

    float acc[4][4] = {};

    for (int k0 = 0; k0 < HD; k0 += 32) {
        float4 xa = *(const float4*)&src[lrow * HD + k0 + lk4];
        float4 xb = *(const float4*)&src[(lrow + 32) * HD + k0 + lk4];
        float4 wa = *(const float4*)&W[(size_t)(col0 + lrow) * HD + k0 + lk4];
        float4 wb = *(const float4*)&W[(size_t)(col0 + lrow + 32) * HD + k0 + lk4];
        __syncthreads();
        Xs[lrow][lk4+0]=xa.x; Xs[lrow][lk4+1]=xa.y; Xs[lrow][lk4+2]=xa.z; Xs[lrow][lk4+3]=xa.w;
        Xs[lrow+32][lk4+0]=xb.x; Xs[lrow+32][lk4+1]=xb.y; Xs[lrow+32][lk4+2]=xb.z; Xs[lrow+32][lk4+3]=xb.w;
        Ws[lrow][lk4+0]=wa.x; Ws[lrow][lk4+1]=wa.y; Ws[lrow][lk4+2]=wa.z; Ws[lrow][lk4+3]=wa.w;
        Ws[lrow+32][lk4+0]=wb.x; Ws[lrow+32][lk4+1]=wb.y; Ws[lrow+32][lk4+2]=wb.z; Ws[lrow+32][lk4+3]=wb.w;
        __syncthreads();
        #pragma unroll
        for (int kk = 0; kk < 32; kk++) {
            float xr[4], wc[4];
            #pragma unroll
            for (int i = 0; i < 4; i++) xr[i] = Xs[ty * 4 + i][kk];
            #pragma unroll
            for (int j = 0; j < 4; j++) wc[j] = Ws[tx * 4 + j][kk];
            #pragma unroll
            for (int i = 0; i < 4; i++)
                #pragma unroll
                for (int j = 0; j < 4; j++)
                    acc[i][j] = fmaf(xr[i], wc[j], acc[i][j]);
        }
    }
    #pragma unroll
    for (int i = 0; i < 4; i++) {
        float4 o = make_float4(acc[i][0], acc[i][1], acc[i][2], acc[i][3]);
        *(float4*)&outp[(size_t)(ty * 4 + i) * H3 + col0 + tx * 4] = o;
    }
}

// ---------------- GRU gate fusion: h = (1-z)*n + z*h ----------------
__global__ __launch_bounds__(256) void gru_fuse(
    const float* __restrict__ gi, const float* __restrict__ gh,
    const float* __restrict__ bih, const float* __restrict__ bhh,
    float* __restrict__ h)
{
    int b = blockIdx.x;
    int base = threadIdx.x * 4;
    #pragma unroll
    for (int u = 0; u < 4; u++) {
        int j = base + u;
        float ir = gi[(size_t)b * H3 + j]          + bih[j];
        float iz = gi[(size_t)b * H3 + HD + j]     + bih[HD + j];
        float in_ = gi[(size_t)b * H3 + 2*HD + j]  + bih[2*HD + j];
        float hr = gh[(size_t)b * H3 + j]          + bhh[j];
        float hz = gh[(size_t)b * H3 + HD + j]     + bhh[HD + j];
        float hn = gh[(size_t)b * H3 + 2*HD + j]   + bhh[2*HD + j];
        float r = sigmoidf_(ir + hr);
        float z = sigmoidf_(iz + hz);
        float n = tanhf(in_ + r * hn);
        float hv = h[(size_t)b * HD + j];
        h[(size_t)b * HD + j] = (1.0f - z) * n + z * hv;
    }
}

// ---------------- logits + per-block argmax ----------------
// 250 blocks, each: 64x128 tile of logits = H[64,1024] @ Wout[v0:v0+128,:]^T
__global__ __launch_bounds__(256) void logits_argmax(
    const float* __restrict__ Hc, const float* __restrict__ Wout,
    const float* __restrict__ bout,
    float* __restrict__ bval, int* __restrict__ bidx)
{
    int col0 = blockIdx.x * 128;
    __shared__ float Hs[64][33];
    __shared__ float Ws[128][33];

    int tid  = threadIdx.x;
    int ty   = tid >> 5, tx = tid & 31;   // 8x32 threads, each 8x4 outputs
    int lrow = tid >> 3;                  // 0..31
    int lk4  = (tid & 7) << 2;

    float acc[8][4] = {};

    for (int k0 = 0; k0 < HD; k0 += 32) {
        float4 ha = *(const float4*)&Hc[lrow * HD + k0 + lk4];
        float4 hb = *(const float4*)&Hc[(lrow + 32) * HD + k0 + lk4];
        float4 w0 = *(const float4*)&Wout[(size_t)(col0 + lrow)      * HD + k0 + lk4];
        float4 w1 = *(const float4*)&Wout[(size_t)(col0 + lrow + 32) * HD + k0 + lk4];
        float4 w2 = *(const float4*)&Wout[(size_t)(col0 + lrow + 64) * HD + k0 + lk4];
        float4 w3 = *(const float4*)&Wout[(size_t)(col0 + lrow + 96) * HD + k0 + lk4];
        __syncthreads();
        Hs[lrow][lk4+0]=ha.x; Hs[lrow][lk4+1]=ha.y; Hs[lrow][lk4+2]=ha.z; Hs[lrow][lk4+3]=ha.w;
        Hs[lrow+32][lk4+0]=hb.x; Hs[lrow+32][lk4+1]=hb.y; Hs[lrow+32][lk4+2]=hb.z; Hs[lrow+32][lk4+3]=hb.w;
        Ws[lrow][lk4+0]=w0.x; Ws[lrow][lk4+1]=w0.y; Ws[lrow][lk4+2]=w0.z; Ws[lrow][lk4+3]=w0.w;
        Ws[lrow+32][lk4+0]=w1.x; Ws[lrow+32][lk4+1]=w1.y; Ws[lrow+32][lk4+2]=w1.z; Ws[lrow+32][lk4+3]=w1.w;
        Ws[lrow+64][lk4+0]=w2.x; Ws[lrow+64][lk4+1]=w2.y; Ws[lrow+64][lk4+2]=w2.z; Ws[lrow+64][lk4+3]=w2.w;
        Ws[lrow+96][lk4+0]=w3.x; Ws[lrow+96][lk4+1]=w3.y; Ws[lrow+96][lk4+2]=w3.z; Ws[lrow+96][lk4+3]=w3.w;
        __syncthreads();
        #pragma unroll
        for (int kk = 0; kk < 32; kk++) {
            float hv[8], wv[4];
            #pragma unroll
            for (int i = 0; i < 8; i++) hv[i] = Hs[ty * 8 + i][kk];
            #pragma unroll
            for (int j = 0; j < 4; j++) wv[j] = Ws[tx * 4 + j][kk];
            #pragma unroll
            for (int i = 0; i < 8; i++)
                #pragma unroll
                for (int j = 0; j < 4; j++)
                    acc[i][j] = fmaf(hv[i], wv[j], acc[i][j]);
        }
    }

    float bo[4];
    #pragma unroll
    for (int j = 0; j < 4; j++) bo[j] = bout[col0 + tx * 4 + j];

    #pragma unroll
    for (int i = 0; i < 8; i++) {
        int r = ty * 8 + i;
        float bv = -FLT_MAX; int bi_ = 0x7fffffff;
        #pragma unroll
        for (int j = 0; j < 4; j++) {
            int v = col0 + tx * 4 + j;
            float val = acc[i][j] + bo[j];
            if (val > bv || (val == bv && v < bi_)) { bv = val; bi_ = v; }
        }
        for (int off = 16; off > 0; off >>= 1) {
            float ov = __shfl_down(bv, off, 32);
            int   oi = __shfl_down(bi_, off, 32);
            if (ov > bv || (ov == bv && oi < bi_)) { bv = ov; bi_ = oi; }
        }
        if (tx == 0) {
            bval[blockIdx.x * 64 + r] = bv;
            bidx[blockIdx.x * 64 + r] = bi_;
        }
    }
}

// ---------------- argmax reduce across 250 blocks + embedding gather ----------------
__global__ __launch_bounds__(256) void argmax_reduce_gather(
    const float* __restrict__ bval, const int* __restrict__ bidx,
    const float* __restrict__ emb, int* __restrict__ resps, int t,
    float* __restrict__ x)
{
    int b = blockIdx.x;
    int tid = threadIdx.x;
    float bv = -FLT_MAX; int bi_ = 0x7fffffff;
    if (tid < 250) { bv = bval[tid * 64 + b]; bi_ = bidx[tid * 64 + b]; }
    for (int off = 32; off > 0; off >>= 1) {
        float ov = __shfl_down(bv, off);
        int   oi = __shfl_down(bi_, off);
        if (ov > bv || (ov == bv && oi < bi_)) { bv = ov; bi_ = oi; }
    }
    __shared__ float sv[4];
    __shared__ int   si[4];
    __shared__ int   stok;
    int wid = tid >> 6;
    if ((tid & 63) == 0) { sv[wid] = bv; si[wid] = bi_; }
    __syncthreads();
    if (tid == 0) {
        bv = sv[0]; bi_ = si[0];
        for (int w = 1; w < 4; w++)
            if (sv[w] > bv || (sv[w] == bv && si[w] < bi_)) { bv = sv[w]; bi_ = si[w]; }
        stok = bi_;
        resps[b * TSTEPS + t] = bi_;
    }
    __syncthreads();
    int tok = stok;
    float4 e = *(const float4*)&emb[(size_t)tok * HD + tid * 4];
    *(float4*)&x[b * HD + tid * 4] = e;
}

// ---------------- resp_lens ----------------
__global__ void resp_lens_kernel(const int* __restrict__ resps, int* __restrict__ lens)
{
    int b = threadIdx.x;
    if (b >= NB) return;
    int len = TSTEPS + 1;
    for (int t = TSTEPS - 1; t >= 0; t--)
        if (resps[b * TSTEPS + t] == 2) len = t + 1;
    lens[b] = len;
}

extern "C" void kernel_launch(void* const* d_in, const int* in_sizes, int n_in,
                              void* d_out, int out_size, void* d_ws, size_t ws_size,
                              hipStream_t stream) {
    const float* zs   = (const float*)d_in[0];
    const float* cs   = (const float*)d_in[1];
    const float* emb  = (const float*)d_in[2];
    const float* Wih  = (const float*)d_in[3];
    const float* Whh  = (const float*)d_in[4];
    const float* bih  = (const float*)d_in[5];
    const float* bhh  = (const float*)d_in[6];
    const float* Wout = (const float*)d_in[7];
    const float* bout = (const float*)d_in[8];
    int* out = (int*)d_out;  // [64*32 resps][64 lens], int32

    char* ws = (char*)d_ws;
    float* X    = (float*)ws; ws += (size_t)NB * HD * 4;
    float* Hbuf = (float*)ws; ws += (size_t)NB * HD * 4;
    float* gi   = (float*)ws; ws += (size_t)NB * H3 * 4;
    float* gh   = (float*)ws; ws += (size_t)NB * H3 * 4;
    float* bval = (float*)ws; ws += (size_t)250 * 64 * 4;
    int*   bidx = (int*)ws;   ws += (size_t)250 * 64 * 4;

    init_kernel<<<NB, 256, 0, stream>>>(zs, cs, emb, Hbuf, X);
    for (int t = 0; t < TSTEPS; t++) {
        gates_gemm<<<96, 256, 0, stream>>>(X, Hbuf, Wih, Whh, gi, gh);
        gru_fuse<<<NB, 256, 0, stream>>>(gi, gh, bih, bhh, Hbuf);
        logits_argmax<<<250, 256, 0, stream>>>(Hbuf, Wout, bout, bval, bidx);
        argmax_reduce_gather<<<NB, 256, 0, stream>>>(bval, bidx, emb, out, t, X);
    }
    resp_lens_kernel<<<1, 64, 0, stream>>>(out, out + NB * TSTEPS);
}